// Round 9
// baseline (324.699 us; speedup 1.0000x reference)
//
#include <hip/hip_runtime.h>
#include <math.h>

#define BSZ 8192
#define DDIM 512
#define EMA_C 0.99
// acc is computed directly in logit scale: each side scaled by 8/||x|| so
// acc = 64*cos. 8 is an exact power of two -> scaling is lossless in fp16/fp32.
#define SC 64.0f
#define NFINAL 32

typedef _Float16 f16;
typedef _Float16 half8 __attribute__((ext_vector_type(8)));
typedef float f32x4 __attribute__((ext_vector_type(4)));

__device__ __forceinline__ void gload16(const void* g, void* l) {
    __builtin_amdgcn_global_load_lds(
        (const __attribute__((address_space(1))) void*)g,
        (__attribute__((address_space(3))) void*)l, 16, 0, 0);
}

// Normalize rows, scale by 8/||x||, fp16 split. A-side (feature1): hi only.
// B-side (feature2): hi + lo. 2-term GEMM: a*b ~= ah*bh + ah*bl (al*bh term
// dropped: residual ~4e-4 logit -> ~1e-5 abs in the final mean loss).
// Also zeroes the stats region (pos/neg/Tsum/lossAcc/ticket).
__global__ void prep_kernel(const float* __restrict__ f1,
                            const float* __restrict__ f2,
                            f16* __restrict__ Ah,
                            f16* __restrict__ Bh, f16* __restrict__ Bl,
                            float* __restrict__ stats) {
    if (blockIdx.y == 0 && blockIdx.x < 25) {
        int idx = blockIdx.x * 256 + threadIdx.x;
        if (idx < (3 * BSZ + 4) / 4)
            reinterpret_cast<float4*>(stats)[idx] = make_float4(0.f, 0.f, 0.f, 0.f);
    }
    const int w = threadIdx.x >> 6, l = threadIdx.x & 63;
    const int row = blockIdx.x * 4 + w;
    const bool isA = (blockIdx.y == 0);
    const float* src = isA ? f1 : f2;
    f16* dh = isA ? Ah : Bh;
    const float4* p = reinterpret_cast<const float4*>(src + (size_t)row * DDIM);
    float4 v0 = p[l * 2], v1 = p[l * 2 + 1];
    float s = v0.x * v0.x + v0.y * v0.y + v0.z * v0.z + v0.w * v0.w +
              v1.x * v1.x + v1.y * v1.y + v1.z * v1.z + v1.w * v1.w;
#pragma unroll
    for (int off = 32; off; off >>= 1) s += __shfl_xor(s, off);
    const float g = 8.0f / sqrtf(s);
    float x[8] = {v0.x, v0.y, v0.z, v0.w, v1.x, v1.y, v1.z, v1.w};
    half8 h8, l8;
#pragma unroll
    for (int e = 0; e < 8; ++e) {
        float xs = x[e] * g;
        f16 hi = (f16)xs;
        h8[e] = hi;
        l8[e] = (f16)(xs - (float)hi);
    }
    *reinterpret_cast<half8*>(dh + (size_t)row * DDIM + l * 8) = h8;
    if (!isA)
        *reinterpret_cast<half8*>(Bl + (size_t)row * DDIM + l * 8) = l8;
}

// Block tile 256(M) x 128(N), BK=32, 4 waves (2x2) of 128x64 each,
// MFMA 16x16x32 f16, 2-term: acc += ah*bh + ah*bl.
// Single-buffered LDS 32KB, compiler-scheduled, lb(256,2) -> 2 blocks/CU
// (64KB LDS/CU, no spill; cross-block overlap covers the barrier drain —
// R3/R8-proven regime; lb(256,3) spills the accumulator, R7).
__launch_bounds__(256, 2)
__global__ void gemm_pass_kernel(const f16* __restrict__ Ah,
                                 const f16* __restrict__ Bh, const f16* __restrict__ Bl,
                                 const int* __restrict__ label,
                                 float* __restrict__ pos,
                                 float* __restrict__ negv,
                                 float* __restrict__ Tsum) {
    // LDS: Ah[256][32] (16KB) + Bh[128][32] (8KB) + Bl[128][32] (8KB)
    // f16; 64-B rows; 16B slot s of row r holds k-group s ^ ((r>>1)&3).
    __shared__ __align__(16) char LDS[32768];
    char* AhL = LDS;
    char* BhL = LDS + 16384;
    char* BlL = LDS + 24576;

    const int t = threadIdx.x, w = t >> 6, l = t & 63;
    const int rowBase = blockIdx.y * 256;
    const int colBase = blockIdx.x * 128;

    // ---- staging source addressing (pre-swizzled so LDS dest is linear) ----
    // gload dest = region + q*1024 + lane*16 -> row 16q+(l>>2), slot l&3
    //   -> k-group kg = (l&3) ^ ((l>>3)&3)
    const int kg = (l & 3) ^ ((l >> 3) & 3);
    const int rsub = l >> 2;  // 0..15

    // A: 16 q-tiles (256 rows), 4 per wave; B: 8 q-tiles (128 rows), 2 per wave
    const int qA0 = 4 * w, qA1 = 4 * w + 1, qA2 = 4 * w + 2, qA3 = 4 * w + 3;
    const int qB0 = 2 * w, qB1 = 2 * w + 1;

    const f16* pA0 = Ah + (size_t)(rowBase + 16 * qA0 + rsub) * DDIM + kg * 8;
    const f16* pA1 = Ah + (size_t)(rowBase + 16 * qA1 + rsub) * DDIM + kg * 8;
    const f16* pA2 = Ah + (size_t)(rowBase + 16 * qA2 + rsub) * DDIM + kg * 8;
    const f16* pA3 = Ah + (size_t)(rowBase + 16 * qA3 + rsub) * DDIM + kg * 8;
    const f16* pBh0 = Bh + (size_t)(colBase + 16 * qB0 + rsub) * DDIM + kg * 8;
    const f16* pBh1 = Bh + (size_t)(colBase + 16 * qB1 + rsub) * DDIM + kg * 8;
    const f16* pBl0 = Bl + (size_t)(colBase + 16 * qB0 + rsub) * DDIM + kg * 8;
    const f16* pBl1 = Bl + (size_t)(colBase + 16 * qB1 + rsub) * DDIM + kg * 8;

    char* dA0 = AhL + qA0 * 1024;
    char* dA1 = AhL + qA1 * 1024;
    char* dA2 = AhL + qA2 * 1024;
    char* dA3 = AhL + qA3 * 1024;
    char* dBh0 = BhL + qB0 * 1024;
    char* dBh1 = BhL + qB1 * 1024;
    char* dBl0 = BlL + qB0 * 1024;
    char* dBl1 = BlL + qB1 * 1024;

    // ---- fragment read addressing ----
    const int wrow = w >> 1, wcol = w & 1;   // 2x2 wave grid
    const int ar = l & 15;
    const int ssw = (l >> 4) ^ ((l >> 1) & 3);  // slot swizzle for frag reads

    f32x4 acc[8][4];
#pragma unroll
    for (int rt = 0; rt < 8; ++rt)
#pragma unroll
        for (int ct = 0; ct < 4; ++ct) acc[rt][ct] = (f32x4){0.f, 0.f, 0.f, 0.f};

    for (int k0 = 0; k0 < DDIM; k0 += 32) {
        __syncthreads();
        gload16(pA0 + k0, dA0);
        gload16(pA1 + k0, dA1);
        gload16(pA2 + k0, dA2);
        gload16(pA3 + k0, dA3);
        gload16(pBh0 + k0, dBh0);
        gload16(pBh1 + k0, dBh1);
        gload16(pBl0 + k0, dBl0);
        gload16(pBl1 + k0, dBl1);
        __syncthreads();

        half8 bhf[4], blf[4];
#pragma unroll
        for (int ct = 0; ct < 4; ++ct) {
            const int off = (wcol * 64 + ct * 16 + ar) * 64 + ssw * 16;
            bhf[ct] = *reinterpret_cast<const half8*>(BhL + off);
            blf[ct] = *reinterpret_cast<const half8*>(BlL + off);
        }
#pragma unroll
        for (int rt = 0; rt < 8; ++rt) {
            const int off = (wrow * 128 + rt * 16 + ar) * 64 + ssw * 16;
            half8 ah = *reinterpret_cast<const half8*>(AhL + off);
#pragma unroll
            for (int ct = 0; ct < 4; ++ct) {
                acc[rt][ct] = __builtin_amdgcn_mfma_f32_16x16x32_f16(ah, bhf[ct], acc[rt][ct], 0, 0, 0);
                acc[rt][ct] = __builtin_amdgcn_mfma_f32_16x16x32_f16(ah, blf[ct], acc[rt][ct], 0, 0, 0);
            }
        }
    }

    // ---- epilogue: clip, mask, exp, per-row sum/max (R5-verified mapping) ----
    // C/D: col = lane&15, row = (lane>>4)*4 + reg  [m89-verified layout]
    const int rowB2 = rowBase + wrow * 128;
    const int colB2 = colBase + wcol * 64;
    const int cl = l & 15, h = l >> 4;

    int lcs[4];
#pragma unroll
    for (int ct = 0; ct < 4; ++ct) lcs[ct] = label[colB2 + ct * 16 + cl];

    float psum[8][4], pmax[8][4];
#pragma unroll
    for (int rt = 0; rt < 8; ++rt)
#pragma unroll
        for (int reg = 0; reg < 4; ++reg) { psum[rt][reg] = 0.f; pmax[rt][reg] = 0.f; }

#pragma unroll
    for (int rt = 0; rt < 8; ++rt) {
        int lr[4];
#pragma unroll
        for (int reg = 0; reg < 4; ++reg) lr[reg] = label[rowB2 + rt * 16 + h * 4 + reg];
#pragma unroll
        for (int ct = 0; ct < 4; ++ct) {
            const int gcol = colB2 + ct * 16 + cl;
#pragma unroll
            for (int reg = 0; reg < 4; ++reg) {
                float v = acc[rt][ct][reg];
                v = fminf(fmaxf(v, -SC), SC);  // clip in logit units (+-64)
                const int grow = rowB2 + rt * 16 + h * 4 + reg;
                if (grow == gcol) {
                    pos[grow] = v;  // scaled diag; exactly one writer chip-wide
                } else {
                    if (lr[reg] == lcs[ct]) v = 0.0f;  // same-label mask
                    psum[rt][reg] += __expf(v);        // e^(64*cos)
                    pmax[rt][reg] = fmaxf(pmax[rt][reg], v);
                }
            }
        }
    }

#pragma unroll
    for (int rt = 0; rt < 8; ++rt)
#pragma unroll
        for (int reg = 0; reg < 4; ++reg) {
            float s = psum[rt][reg], mx = pmax[rt][reg];
#pragma unroll
            for (int m = 1; m <= 8; m <<= 1) {
                s += __shfl_xor(s, m);
                mx = fmaxf(mx, __shfl_xor(mx, m));
            }
            if (cl == 0) {
                const int grow = rowB2 + rt * 16 + h * 4 + reg;
                atomicAdd(&Tsum[grow], s);
                // values >= 0 -> int compare == float compare; init bits 0.0f
                atomicMax(reinterpret_cast<int*>(&negv[grow]), __float_as_int(mx));
            }
        }
}

// 32 blocks x 256 threads: each thread owns exactly one row. Every block
// redundantly computes the (bit-identical) m-sum; per-row loss in double;
// block partial -> f64 atomicAdd; last block (ticket) writes out.
__global__ void final_kernel(const float* __restrict__ pos,
                             const float* __restrict__ negv,
                             const float* __restrict__ Tsum,
                             double* __restrict__ lossAcc,
                             int* __restrict__ ticket,
                             float* __restrict__ out) {
    __shared__ double sd[256];
    const int t = threadIdx.x;

    // ---- mLogit = SC*m = EMA * sum(pos-neg)/B ----
    double s = 0.0;
    for (int i = t; i < BSZ; i += 256) s += (double)pos[i] - (double)negv[i];
    sd[t] = s;
    __syncthreads();
    for (int off = 128; off; off >>= 1) {
        if (t < off) sd[t] += sd[t + off];
        __syncthreads();
    }
    const double mLogit = EMA_C * sd[0] / BSZ;
    __syncthreads();

    // ---- one row per thread: loss = log(T + exp(d)) - d, stable ----
    const int row = blockIdx.x * 256 + t;  // NFINAL*256 == BSZ
    double d  = (double)pos[row] - mLogit;
    double lt = log((double)Tsum[row]);
    double l;
    if (d >= lt) l = log1p(exp(lt - d));
    else         l = (lt - d) + log1p(exp(d - lt));
    sd[t] = l;
    __syncthreads();
    for (int off = 128; off; off >>= 1) {
        if (t < off) sd[t] += sd[t + off];
        __syncthreads();
    }
    if (t == 0) {
        atomicAdd(lossAcc, sd[0]);
        __threadfence();
        int done = atomicAdd(ticket, 1);
        if (done == NFINAL - 1) {
            double total = atomicAdd(lossAcc, 0.0);  // RMW read: coherent total
            out[0] = (float)(total / BSZ);
        }
    }
}

extern "C" void kernel_launch(void* const* d_in, const int* in_sizes, int n_in,
                              void* d_out, int out_size, void* d_ws, size_t ws_size,
                              hipStream_t stream) {
    const float* f1    = (const float*)d_in[0];
    const float* f2    = (const float*)d_in[1];
    const int*   label = (const int*)d_in[2];
    float* out = (float*)d_out;

    // ws layout: pos[B], neg[B], Tsum[B] (f32), lossAcc (f64), ticket (i32),
    // pad to 16B, then Ah/Bh/Bl fp16 matrices (3 x 8M).
    float* stats = (float*)d_ws;
    float* pos   = stats;
    float* neg   = stats + BSZ;
    float* Tsum  = stats + 2 * BSZ;
    double* lossAcc = (double*)(stats + 3 * BSZ);       // byte 98304, 8-aligned
    int* ticket  = (int*)(stats + 3 * BSZ + 2);
    f16* Ah = (f16*)((char*)d_ws + 3 * BSZ * sizeof(float) + 16);
    f16* Bh = Ah + (size_t)BSZ * DDIM;
    f16* Bl = Bh + (size_t)BSZ * DDIM;

    prep_kernel<<<dim3(BSZ / 4, 2), dim3(256), 0, stream>>>(f1, f2, Ah, Bh, Bl, stats);

    gemm_pass_kernel<<<dim3(BSZ / 128, BSZ / 256), dim3(256), 0, stream>>>(
        Ah, Bh, Bl, label, pos, neg, Tsum);

    final_kernel<<<dim3(NFINAL), dim3(256), 0, stream>>>(pos, neg, Tsum, lossAcc, ticket, out);
}

// Round 10
// 314.130 us; speedup vs baseline: 1.0336x; 1.0336x over previous
//
#include <hip/hip_runtime.h>
#include <math.h>

#define BSZ 8192
#define DDIM 512
#define EMA_C 0.99
// acc is computed directly in logit scale: each side scaled by 8/||x|| so
// acc = 64*cos. 8 is an exact power of two -> scaling is lossless in fp16/fp32.
#define SC 64.0f
#define NFINAL 32

typedef _Float16 f16;
typedef _Float16 half8 __attribute__((ext_vector_type(8)));
typedef float f32x4 __attribute__((ext_vector_type(4)));

__device__ __forceinline__ void gload16(const void* g, void* l) {
    __builtin_amdgcn_global_load_lds(
        (const __attribute__((address_space(1))) void*)g,
        (__attribute__((address_space(3))) void*)l, 16, 0, 0);
}

// Normalize rows, scale by 8/||x||, fp16 split. A-side (feature1): hi only.
// B-side (feature2): hi + lo. 2-term GEMM: a*b ~= ah*bh + ah*bl (al*bh term
// dropped: residual ~4e-4 logit -> ~1e-5 abs in the final mean loss).
// Also zeroes the stats region (pos/neg/Tsum/lossAcc/ticket).
__global__ void prep_kernel(const float* __restrict__ f1,
                            const float* __restrict__ f2,
                            f16* __restrict__ Ah,
                            f16* __restrict__ Bh, f16* __restrict__ Bl,
                            float* __restrict__ stats) {
    if (blockIdx.y == 0 && blockIdx.x < 25) {
        int idx = blockIdx.x * 256 + threadIdx.x;
        if (idx < (3 * BSZ + 4) / 4)
            reinterpret_cast<float4*>(stats)[idx] = make_float4(0.f, 0.f, 0.f, 0.f);
    }
    const int w = threadIdx.x >> 6, l = threadIdx.x & 63;
    const int row = blockIdx.x * 4 + w;
    const bool isA = (blockIdx.y == 0);
    const float* src = isA ? f1 : f2;
    f16* dh = isA ? Ah : Bh;
    const float4* p = reinterpret_cast<const float4*>(src + (size_t)row * DDIM);
    float4 v0 = p[l * 2], v1 = p[l * 2 + 1];
    float s = v0.x * v0.x + v0.y * v0.y + v0.z * v0.z + v0.w * v0.w +
              v1.x * v1.x + v1.y * v1.y + v1.z * v1.z + v1.w * v1.w;
#pragma unroll
    for (int off = 32; off; off >>= 1) s += __shfl_xor(s, off);
    const float g = 8.0f / sqrtf(s);
    float x[8] = {v0.x, v0.y, v0.z, v0.w, v1.x, v1.y, v1.z, v1.w};
    half8 h8, l8;
#pragma unroll
    for (int e = 0; e < 8; ++e) {
        float xs = x[e] * g;
        f16 hi = (f16)xs;
        h8[e] = hi;
        l8[e] = (f16)(xs - (float)hi);
    }
    *reinterpret_cast<half8*>(dh + (size_t)row * DDIM + l * 8) = h8;
    if (!isA)
        *reinterpret_cast<half8*>(Bl + (size_t)row * DDIM + l * 8) = l8;
}

// Block tile 256(M) x 128(N), BK=64, 4 waves (2x2) of 128x64 each,
// MFMA 16x16x32 f16, 2-term: acc += ah*bh + ah*bl.
// 8 K-iterations (was 16 at BK=32): R8 vs R9 showed wall time is invariant
// to MFMA count -> latency-chain-bound; halving the chain count is the lever.
// LDS 64KB single-buffered, lb(256,2) -> 2 blocks/CU (128KB LDS, reg cap 256
// >= ~240 need: no spill. lb(256,3) would spill the accumulator — R7).
__launch_bounds__(256, 2)
__global__ void gemm_pass_kernel(const f16* __restrict__ Ah,
                                 const f16* __restrict__ Bh, const f16* __restrict__ Bl,
                                 const int* __restrict__ label,
                                 float* __restrict__ pos,
                                 float* __restrict__ negv,
                                 float* __restrict__ Tsum) {
    // LDS: Ah[256][64] (32KB) + Bh[128][64] (16KB) + Bl[128][64] (16KB), f16.
    // 128-B rows = 8 x 16B slots; slot s of row r holds k-group s ^ (r&7).
    __shared__ __align__(16) char LDS[65536];
    char* AhL = LDS;
    char* BhL = LDS + 32768;
    char* BlL = LDS + 49152;

    const int t = threadIdx.x, w = t >> 6, l = t & 63;
    const int rowBase = blockIdx.y * 256;
    const int colBase = blockIdx.x * 128;

    // ---- staging addressing (pre-swizzled global src; LDS dest linear) ----
    // one gload16/wave = 1024B = 8 rows; dest byte = base + l*16 ->
    // row = 8q + (l>>3), slot = l&7 -> k-group kg = (l&7) ^ (l>>3).
    const int kg = (l & 7) ^ (l >> 3);
    const int rs = l >> 3;  // 0..7
    // wave w owns A q-tiles 8w..8w+7 (rows 64w..64w+63), B q-tiles 4w..4w+3.
    const f16* pA  = Ah + (size_t)(rowBase + 64 * w + rs) * DDIM + kg * 8;
    const f16* pBh = Bh + (size_t)(colBase + 32 * w + rs) * DDIM + kg * 8;
    const f16* pBl = Bl + (size_t)(colBase + 32 * w + rs) * DDIM + kg * 8;

    // ---- fragment read addressing (swizzled reads) ----
    const int wrow = w >> 1, wcol = w & 1;   // 2x2 wave grid
    const int ar = l & 15;
    // k-slice ks (0/1): slot = (ks*4 + (l>>4)) ^ (row&7); row&7 == l&7
    const int ss0 = (((l >> 4) + 0) ^ (l & 7)) * 16;
    const int ss1 = (((l >> 4) + 4) ^ (l & 7)) * 16;

    f32x4 acc[8][4];
#pragma unroll
    for (int rt = 0; rt < 8; ++rt)
#pragma unroll
        for (int ct = 0; ct < 4; ++ct) acc[rt][ct] = (f32x4){0.f, 0.f, 0.f, 0.f};

    for (int k0 = 0; k0 < DDIM; k0 += 64) {
        __syncthreads();
#pragma unroll
        for (int q = 0; q < 8; ++q)
            gload16(pA + (size_t)(8 * q) * DDIM + k0, AhL + w * 8192 + q * 1024);
#pragma unroll
        for (int q = 0; q < 4; ++q) {
            gload16(pBh + (size_t)(8 * q) * DDIM + k0, BhL + w * 4096 + q * 1024);
            gload16(pBl + (size_t)(8 * q) * DDIM + k0, BlL + w * 4096 + q * 1024);
        }
        __syncthreads();

        // ---- k-slice 0 (k0..k0+31) ----
        {
            half8 bhf[4], blf[4];
#pragma unroll
            for (int ct = 0; ct < 4; ++ct) {
                const int r = wcol * 64 + ct * 16 + ar;
                bhf[ct] = *reinterpret_cast<const half8*>(BhL + r * 128 + ss0);
                blf[ct] = *reinterpret_cast<const half8*>(BlL + r * 128 + ss0);
            }
#pragma unroll
            for (int rt = 0; rt < 8; ++rt) {
                const int r = wrow * 128 + rt * 16 + ar;
                half8 ah = *reinterpret_cast<const half8*>(AhL + r * 128 + ss0);
#pragma unroll
                for (int ct = 0; ct < 4; ++ct) {
                    acc[rt][ct] = __builtin_amdgcn_mfma_f32_16x16x32_f16(ah, bhf[ct], acc[rt][ct], 0, 0, 0);
                    acc[rt][ct] = __builtin_amdgcn_mfma_f32_16x16x32_f16(ah, blf[ct], acc[rt][ct], 0, 0, 0);
                }
            }
        }
        // ---- k-slice 1 (k0+32..k0+63) ----
        {
            half8 bhf[4], blf[4];
#pragma unroll
            for (int ct = 0; ct < 4; ++ct) {
                const int r = wcol * 64 + ct * 16 + ar;
                bhf[ct] = *reinterpret_cast<const half8*>(BhL + r * 128 + ss1);
                blf[ct] = *reinterpret_cast<const half8*>(BlL + r * 128 + ss1);
            }
#pragma unroll
            for (int rt = 0; rt < 8; ++rt) {
                const int r = wrow * 128 + rt * 16 + ar;
                half8 ah = *reinterpret_cast<const half8*>(AhL + r * 128 + ss1);
#pragma unroll
                for (int ct = 0; ct < 4; ++ct) {
                    acc[rt][ct] = __builtin_amdgcn_mfma_f32_16x16x32_f16(ah, bhf[ct], acc[rt][ct], 0, 0, 0);
                    acc[rt][ct] = __builtin_amdgcn_mfma_f32_16x16x32_f16(ah, blf[ct], acc[rt][ct], 0, 0, 0);
                }
            }
        }
    }

    // ---- epilogue: clip, mask, exp, per-row sum/max (R5/R9-verified mapping) ----
    // C/D: col = lane&15, row = (lane>>4)*4 + reg  [m89-verified layout]
    const int rowB2 = rowBase + wrow * 128;
    const int colB2 = colBase + wcol * 64;
    const int cl = l & 15, h = l >> 4;

    int lcs[4];
#pragma unroll
    for (int ct = 0; ct < 4; ++ct) lcs[ct] = label[colB2 + ct * 16 + cl];

    float psum[8][4], pmax[8][4];
#pragma unroll
    for (int rt = 0; rt < 8; ++rt)
#pragma unroll
        for (int reg = 0; reg < 4; ++reg) { psum[rt][reg] = 0.f; pmax[rt][reg] = 0.f; }

#pragma unroll
    for (int rt = 0; rt < 8; ++rt) {
        int lr[4];
#pragma unroll
        for (int reg = 0; reg < 4; ++reg) lr[reg] = label[rowB2 + rt * 16 + h * 4 + reg];
#pragma unroll
        for (int ct = 0; ct < 4; ++ct) {
            const int gcol = colB2 + ct * 16 + cl;
#pragma unroll
            for (int reg = 0; reg < 4; ++reg) {
                float v = acc[rt][ct][reg];
                v = fminf(fmaxf(v, -SC), SC);  // clip in logit units (+-64)
                const int grow = rowB2 + rt * 16 + h * 4 + reg;
                if (grow == gcol) {
                    pos[grow] = v;  // scaled diag; exactly one writer chip-wide
                } else {
                    if (lr[reg] == lcs[ct]) v = 0.0f;  // same-label mask
                    psum[rt][reg] += __expf(v);        // e^(64*cos)
                    pmax[rt][reg] = fmaxf(pmax[rt][reg], v);
                }
            }
        }
    }

#pragma unroll
    for (int rt = 0; rt < 8; ++rt)
#pragma unroll
        for (int reg = 0; reg < 4; ++reg) {
            float s = psum[rt][reg], mx = pmax[rt][reg];
#pragma unroll
            for (int m = 1; m <= 8; m <<= 1) {
                s += __shfl_xor(s, m);
                mx = fmaxf(mx, __shfl_xor(mx, m));
            }
            if (cl == 0) {
                const int grow = rowB2 + rt * 16 + h * 4 + reg;
                atomicAdd(&Tsum[grow], s);
                // values >= 0 -> int compare == float compare; init bits 0.0f
                atomicMax(reinterpret_cast<int*>(&negv[grow]), __float_as_int(mx));
            }
        }
}

// 32 blocks x 256 threads: each thread owns exactly one row. Every block
// redundantly computes the (bit-identical) m-sum; per-row loss in double;
// block partial -> f64 atomicAdd; last block (ticket) writes out.
__global__ void final_kernel(const float* __restrict__ pos,
                             const float* __restrict__ negv,
                             const float* __restrict__ Tsum,
                             double* __restrict__ lossAcc,
                             int* __restrict__ ticket,
                             float* __restrict__ out) {
    __shared__ double sd[256];
    const int t = threadIdx.x;

    // ---- mLogit = SC*m = EMA * sum(pos-neg)/B ----
    double s = 0.0;
    for (int i = t; i < BSZ; i += 256) s += (double)pos[i] - (double)negv[i];
    sd[t] = s;
    __syncthreads();
    for (int off = 128; off; off >>= 1) {
        if (t < off) sd[t] += sd[t + off];
        __syncthreads();
    }
    const double mLogit = EMA_C * sd[0] / BSZ;
    __syncthreads();

    // ---- one row per thread: loss = log(T + exp(d)) - d, stable ----
    const int row = blockIdx.x * 256 + t;  // NFINAL*256 == BSZ
    double d  = (double)pos[row] - mLogit;
    double lt = log((double)Tsum[row]);
    double l;
    if (d >= lt) l = log1p(exp(lt - d));
    else         l = (lt - d) + log1p(exp(d - lt));
    sd[t] = l;
    __syncthreads();
    for (int off = 128; off; off >>= 1) {
        if (t < off) sd[t] += sd[t + off];
        __syncthreads();
    }
    if (t == 0) {
        atomicAdd(lossAcc, sd[0]);
        __threadfence();
        int done = atomicAdd(ticket, 1);
        if (done == NFINAL - 1) {
            double total = atomicAdd(lossAcc, 0.0);  // RMW read: coherent total
            out[0] = (float)(total / BSZ);
        }
    }
}

extern "C" void kernel_launch(void* const* d_in, const int* in_sizes, int n_in,
                              void* d_out, int out_size, void* d_ws, size_t ws_size,
                              hipStream_t stream) {
    const float* f1    = (const float*)d_in[0];
    const float* f2    = (const float*)d_in[1];
    const int*   label = (const int*)d_in[2];
    float* out = (float*)d_out;

    // ws layout: pos[B], neg[B], Tsum[B] (f32), lossAcc (f64), ticket (i32),
    // pad to 16B, then Ah/Bh/Bl fp16 matrices (3 x 8M).
    float* stats = (float*)d_ws;
    float* pos   = stats;
    float* neg   = stats + BSZ;
    float* Tsum  = stats + 2 * BSZ;
    double* lossAcc = (double*)(stats + 3 * BSZ);       // byte 98304, 8-aligned
    int* ticket  = (int*)(stats + 3 * BSZ + 2);
    f16* Ah = (f16*)((char*)d_ws + 3 * BSZ * sizeof(float) + 16);
    f16* Bh = Ah + (size_t)BSZ * DDIM;
    f16* Bl = Bh + (size_t)BSZ * DDIM;

    prep_kernel<<<dim3(BSZ / 4, 2), dim3(256), 0, stream>>>(f1, f2, Ah, Bh, Bl, stats);

    gemm_pass_kernel<<<dim3(BSZ / 128, BSZ / 256), dim3(256), 0, stream>>>(
        Ah, Bh, Bl, label, pos, neg, Tsum);

    final_kernel<<<dim3(NFINAL), dim3(256), 0, stream>>>(pos, neg, Tsum, lossAcc, ticket, out);
}

// Round 11
// 281.903 us; speedup vs baseline: 1.1518x; 1.1143x over previous
//
#include <hip/hip_runtime.h>
#include <math.h>

#define BSZ 8192
#define DDIM 512
#define EMA_C 0.99
// acc is computed directly in logit scale: each side scaled by 8/||x|| so
// acc = 64*cos. 8 is an exact power of two -> scaling is lossless in fp16/fp32.
#define SC 64.0f
#define NFINAL 32

typedef _Float16 f16;
typedef _Float16 half8 __attribute__((ext_vector_type(8)));
typedef float f32x4 __attribute__((ext_vector_type(4)));

__device__ __forceinline__ void gload16(const void* g, void* l) {
    __builtin_amdgcn_global_load_lds(
        (const __attribute__((address_space(1))) void*)g,
        (__attribute__((address_space(3))) void*)l, 16, 0, 0);
}

// Normalize rows, scale by 8/||x||, fp16 split. A-side (feature1): hi only.
// B-side (feature2): hi + lo. 2-term GEMM: a*b ~= ah*bh + ah*bl (al*bh term
// dropped: residual ~4e-4 logit -> ~1e-5 abs in the final mean loss).
// Also zeroes the stats region (pos/neg/Tsum/lossAcc/ticket).
__global__ void prep_kernel(const float* __restrict__ f1,
                            const float* __restrict__ f2,
                            f16* __restrict__ Ah,
                            f16* __restrict__ Bh, f16* __restrict__ Bl,
                            float* __restrict__ stats) {
    if (blockIdx.y == 0 && blockIdx.x < 25) {
        int idx = blockIdx.x * 256 + threadIdx.x;
        if (idx < (3 * BSZ + 4) / 4)
            reinterpret_cast<float4*>(stats)[idx] = make_float4(0.f, 0.f, 0.f, 0.f);
    }
    const int w = threadIdx.x >> 6, l = threadIdx.x & 63;
    const int row = blockIdx.x * 4 + w;
    const bool isA = (blockIdx.y == 0);
    const float* src = isA ? f1 : f2;
    f16* dh = isA ? Ah : Bh;
    const float4* p = reinterpret_cast<const float4*>(src + (size_t)row * DDIM);
    float4 v0 = p[l * 2], v1 = p[l * 2 + 1];
    float s = v0.x * v0.x + v0.y * v0.y + v0.z * v0.z + v0.w * v0.w +
              v1.x * v1.x + v1.y * v1.y + v1.z * v1.z + v1.w * v1.w;
#pragma unroll
    for (int off = 32; off; off >>= 1) s += __shfl_xor(s, off);
    const float g = 8.0f / sqrtf(s);
    float x[8] = {v0.x, v0.y, v0.z, v0.w, v1.x, v1.y, v1.z, v1.w};
    half8 h8, l8;
#pragma unroll
    for (int e = 0; e < 8; ++e) {
        float xs = x[e] * g;
        f16 hi = (f16)xs;
        h8[e] = hi;
        l8[e] = (f16)(xs - (float)hi);
    }
    *reinterpret_cast<half8*>(dh + (size_t)row * DDIM + l * 8) = h8;
    if (!isA)
        *reinterpret_cast<half8*>(Bl + (size_t)row * DDIM + l * 8) = l8;
}

// Block tile 128 x 128, BK=64, 4 waves (2x2) of 64x64 each, MFMA 16x16x32 f16,
// 2-term: acc += ah*bh + ah*bl.  Occupancy play (R10 post-mortem): acc shrunk
// to 64 AGPR so combined regs ~154 <= 170 = lb(256,3) cap -> 3 blocks/CU
// (LDS 48KB x3 = 144KB), 12 waves/CU — the measured m97 overlap regime.
// (R7 spilled at lb(256,3) because its acc was 128 AGPR -> 232 > 170.)
__launch_bounds__(256, 3)
__global__ void gemm_pass_kernel(const f16* __restrict__ Ah,
                                 const f16* __restrict__ Bh, const f16* __restrict__ Bl,
                                 const int* __restrict__ label,
                                 float* __restrict__ pos,
                                 float* __restrict__ negv,
                                 float* __restrict__ Tsum) {
    // LDS: Ah[128][64] (16KB) + Bh[128][64] (16KB) + Bl[128][64] (16KB), f16.
    // 128-B rows = 8 x 16B slots; slot s of row r holds k-group s ^ (r&7).
    __shared__ __align__(16) char LDS[49152];
    char* AhL = LDS;
    char* BhL = LDS + 16384;
    char* BlL = LDS + 32768;

    const int t = threadIdx.x, w = t >> 6, l = t & 63;
    const int rowBase = blockIdx.y * 128;
    const int colBase = blockIdx.x * 128;

    // ---- staging addressing (pre-swizzled global src; LDS dest linear) ----
    // one gload16/wave = 1024B = 8 rows; dest byte = base + l*16 ->
    // row = 8q + (l>>3), slot = l&7 -> k-group kg = (l&7) ^ (l>>3).
    const int kg = (l & 7) ^ (l >> 3);
    const int rs = l >> 3;  // 0..7
    // wave w stages rows 32w..32w+31 of each region (4 q-tiles of 8 rows).
    const f16* pA  = Ah + (size_t)(rowBase + 32 * w + rs) * DDIM + kg * 8;
    const f16* pBh = Bh + (size_t)(colBase + 32 * w + rs) * DDIM + kg * 8;
    const f16* pBl = Bl + (size_t)(colBase + 32 * w + rs) * DDIM + kg * 8;

    // ---- fragment read addressing (swizzled reads) ----
    const int wrow = w >> 1, wcol = w & 1;   // 2x2 wave grid, wave tile 64x64
    const int ar = l & 15;
    // k-slice ks (0/1): slot = (ks*4 + (l>>4)) ^ (row&7); row&7 == l&7 here
    const int ss0 = (((l >> 4) + 0) ^ (l & 7)) * 16;
    const int ss1 = (((l >> 4) + 4) ^ (l & 7)) * 16;

    f32x4 acc[4][4];
#pragma unroll
    for (int rt = 0; rt < 4; ++rt)
#pragma unroll
        for (int ct = 0; ct < 4; ++ct) acc[rt][ct] = (f32x4){0.f, 0.f, 0.f, 0.f};

    for (int k0 = 0; k0 < DDIM; k0 += 64) {
        __syncthreads();
#pragma unroll
        for (int q = 0; q < 4; ++q) {
            gload16(pA  + (size_t)(8 * q) * DDIM + k0, AhL + w * 4096 + q * 1024);
            gload16(pBh + (size_t)(8 * q) * DDIM + k0, BhL + w * 4096 + q * 1024);
            gload16(pBl + (size_t)(8 * q) * DDIM + k0, BlL + w * 4096 + q * 1024);
        }
        __syncthreads();

        // ---- k-slice 0 (k0..k0+31) ----
        {
            half8 bhf[4], blf[4], ahf[4];
#pragma unroll
            for (int ct = 0; ct < 4; ++ct) {
                const int r = wcol * 64 + ct * 16 + ar;
                bhf[ct] = *reinterpret_cast<const half8*>(BhL + r * 128 + ss0);
                blf[ct] = *reinterpret_cast<const half8*>(BlL + r * 128 + ss0);
            }
#pragma unroll
            for (int rt = 0; rt < 4; ++rt) {
                const int r = wrow * 64 + rt * 16 + ar;
                ahf[rt] = *reinterpret_cast<const half8*>(AhL + r * 128 + ss0);
            }
#pragma unroll
            for (int rt = 0; rt < 4; ++rt)
#pragma unroll
                for (int ct = 0; ct < 4; ++ct) {
                    acc[rt][ct] = __builtin_amdgcn_mfma_f32_16x16x32_f16(ahf[rt], bhf[ct], acc[rt][ct], 0, 0, 0);
                    acc[rt][ct] = __builtin_amdgcn_mfma_f32_16x16x32_f16(ahf[rt], blf[ct], acc[rt][ct], 0, 0, 0);
                }
        }
        // ---- k-slice 1 (k0+32..k0+63) ----
        {
            half8 bhf[4], blf[4], ahf[4];
#pragma unroll
            for (int ct = 0; ct < 4; ++ct) {
                const int r = wcol * 64 + ct * 16 + ar;
                bhf[ct] = *reinterpret_cast<const half8*>(BhL + r * 128 + ss1);
                blf[ct] = *reinterpret_cast<const half8*>(BlL + r * 128 + ss1);
            }
#pragma unroll
            for (int rt = 0; rt < 4; ++rt) {
                const int r = wrow * 64 + rt * 16 + ar;
                ahf[rt] = *reinterpret_cast<const half8*>(AhL + r * 128 + ss1);
            }
#pragma unroll
            for (int rt = 0; rt < 4; ++rt)
#pragma unroll
                for (int ct = 0; ct < 4; ++ct) {
                    acc[rt][ct] = __builtin_amdgcn_mfma_f32_16x16x32_f16(ahf[rt], bhf[ct], acc[rt][ct], 0, 0, 0);
                    acc[rt][ct] = __builtin_amdgcn_mfma_f32_16x16x32_f16(ahf[rt], blf[ct], acc[rt][ct], 0, 0, 0);
                }
        }
    }

    // ---- epilogue: clip, mask, exp, per-row sum/max ----
    // C/D: col = lane&15, row = (lane>>4)*4 + reg  [m89-verified layout]
    const int rowB2 = rowBase + wrow * 64;
    const int colB2 = colBase + wcol * 64;
    const int cl = l & 15, h = l >> 4;

    int lcs[4];
#pragma unroll
    for (int ct = 0; ct < 4; ++ct) lcs[ct] = label[colB2 + ct * 16 + cl];

    float psum[4][4], pmax[4][4];
#pragma unroll
    for (int rt = 0; rt < 4; ++rt)
#pragma unroll
        for (int reg = 0; reg < 4; ++reg) { psum[rt][reg] = 0.f; pmax[rt][reg] = 0.f; }

#pragma unroll
    for (int rt = 0; rt < 4; ++rt) {
        int lr[4];
#pragma unroll
        for (int reg = 0; reg < 4; ++reg) lr[reg] = label[rowB2 + rt * 16 + h * 4 + reg];
#pragma unroll
        for (int ct = 0; ct < 4; ++ct) {
            const int gcol = colB2 + ct * 16 + cl;
#pragma unroll
            for (int reg = 0; reg < 4; ++reg) {
                float v = acc[rt][ct][reg];
                v = fminf(fmaxf(v, -SC), SC);  // clip in logit units (+-64)
                const int grow = rowB2 + rt * 16 + h * 4 + reg;
                if (grow == gcol) {
                    pos[grow] = v;  // scaled diag; exactly one writer chip-wide
                } else {
                    if (lr[reg] == lcs[ct]) v = 0.0f;  // same-label mask
                    psum[rt][reg] += __expf(v);        // e^(64*cos)
                    pmax[rt][reg] = fmaxf(pmax[rt][reg], v);
                }
            }
        }
    }

#pragma unroll
    for (int rt = 0; rt < 4; ++rt)
#pragma unroll
        for (int reg = 0; reg < 4; ++reg) {
            float s = psum[rt][reg], mx = pmax[rt][reg];
#pragma unroll
            for (int m = 1; m <= 8; m <<= 1) {
                s += __shfl_xor(s, m);
                mx = fmaxf(mx, __shfl_xor(mx, m));
            }
            if (cl == 0) {
                const int grow = rowB2 + rt * 16 + h * 4 + reg;
                atomicAdd(&Tsum[grow], s);
                // values >= 0 -> int compare == float compare; init bits 0.0f
                atomicMax(reinterpret_cast<int*>(&negv[grow]), __float_as_int(mx));
            }
        }
}

// 32 blocks x 256 threads: each thread owns exactly one row. Every block
// redundantly computes the (bit-identical) m-sum; per-row loss in double;
// block partial -> f64 atomicAdd; last block (ticket) writes out.
__global__ void final_kernel(const float* __restrict__ pos,
                             const float* __restrict__ negv,
                             const float* __restrict__ Tsum,
                             double* __restrict__ lossAcc,
                             int* __restrict__ ticket,
                             float* __restrict__ out) {
    __shared__ double sd[256];
    const int t = threadIdx.x;

    // ---- mLogit = SC*m = EMA * sum(pos-neg)/B ----
    double s = 0.0;
    for (int i = t; i < BSZ; i += 256) s += (double)pos[i] - (double)negv[i];
    sd[t] = s;
    __syncthreads();
    for (int off = 128; off; off >>= 1) {
        if (t < off) sd[t] += sd[t + off];
        __syncthreads();
    }
    const double mLogit = EMA_C * sd[0] / BSZ;
    __syncthreads();

    // ---- one row per thread: loss = log(T + exp(d)) - d, stable ----
    const int row = blockIdx.x * 256 + t;  // NFINAL*256 == BSZ
    double d  = (double)pos[row] - mLogit;
    double lt = log((double)Tsum[row]);
    double l;
    if (d >= lt) l = log1p(exp(lt - d));
    else         l = (lt - d) + log1p(exp(d - lt));
    sd[t] = l;
    __syncthreads();
    for (int off = 128; off; off >>= 1) {
        if (t < off) sd[t] += sd[t + off];
        __syncthreads();
    }
    if (t == 0) {
        atomicAdd(lossAcc, sd[0]);
        __threadfence();
        int done = atomicAdd(ticket, 1);
        if (done == NFINAL - 1) {
            double total = atomicAdd(lossAcc, 0.0);  // RMW read: coherent total
            out[0] = (float)(total / BSZ);
        }
    }
}

extern "C" void kernel_launch(void* const* d_in, const int* in_sizes, int n_in,
                              void* d_out, int out_size, void* d_ws, size_t ws_size,
                              hipStream_t stream) {
    const float* f1    = (const float*)d_in[0];
    const float* f2    = (const float*)d_in[1];
    const int*   label = (const int*)d_in[2];
    float* out = (float*)d_out;

    // ws layout: pos[B], neg[B], Tsum[B] (f32), lossAcc (f64), ticket (i32),
    // pad to 16B, then Ah/Bh/Bl fp16 matrices (3 x 8M).
    float* stats = (float*)d_ws;
    float* pos   = stats;
    float* neg   = stats + BSZ;
    float* Tsum  = stats + 2 * BSZ;
    double* lossAcc = (double*)(stats + 3 * BSZ);       // byte 98304, 8-aligned
    int* ticket  = (int*)(stats + 3 * BSZ + 2);
    f16* Ah = (f16*)((char*)d_ws + 3 * BSZ * sizeof(float) + 16);
    f16* Bh = Ah + (size_t)BSZ * DDIM;
    f16* Bl = Bh + (size_t)BSZ * DDIM;

    prep_kernel<<<dim3(BSZ / 4, 2), dim3(256), 0, stream>>>(f1, f2, Ah, Bh, Bl, stats);

    gemm_pass_kernel<<<dim3(BSZ / 128, BSZ / 128), dim3(256), 0, stream>>>(
        Ah, Bh, Bl, label, pos, neg, Tsum);

    final_kernel<<<dim3(NFINAL), dim3(256), 0, stream>>>(pos, neg, Tsum, lossAcc, ticket, out);
}